// Round 4
// baseline (7541.155 us; speedup 1.0000x reference)
//
#include <hip/hip_runtime.h>

#define TT 1024
#define DU 256

// workspace layout (bytes)
#define CEX_OFF   0          // bf16 c slots: [8 grp][16 mem][16 b][16 c] (65536 B)
#define HEX_OFF   65536      // bf16 h slots: same layout (65536 B)
#define STMP_OFF  131072     // u32 stamps: [8 grp][16 mem][16 pad] — 64B line per member (8192 B)
#define TST_OFF   139264     // 4 test regions x 8 grp x 4096 B (131072 B)
#define GCON_OFF  270336     // gok[128] u32 @ +0; gpol u32 @ +1024 (2048 B)
#define BLOB_OFF  272384     // 16 member chunks of bf16 weights
#define CHUNK_ELEMS (11*16*256)   // per-member: 11 mats x 16 cols x 256 k

typedef unsigned short ushort_t;
typedef unsigned u32;
typedef unsigned long long u64;
typedef __attribute__((ext_vector_type(8))) short short8;
typedef __attribute__((ext_vector_type(4))) float floatx4;

#define MFMA(a, b, c) __builtin_amdgcn_mfma_f32_16x16x32_bf16((a), (b), (c), 0, 0, 0)

__device__ __forceinline__ ushort_t f2bf(float f) {
  unsigned u = __float_as_uint(f);
  return (ushort_t)((u + 0x7fffu + ((u >> 16) & 1u)) >> 16);
}
__device__ __forceinline__ float sigf(float x) { return 1.0f / (1.0f + __expf(-x)); }
__device__ __forceinline__ float tanhf_(float x) {
  float t = 1.0f - 2.0f / (__expf(2.0f * fabsf(x)) + 1.0f);
  return copysignf(t, x);
}

// ---------------- slow (agent/MALL) exchange: proven baseline path ----------------
__device__ __forceinline__ short8 ldfrag(const ushort_t* p) {
  union { struct { u64 a, b; } q; short8 s; } v;
  v.q.a = __hip_atomic_load((const u64*)p,       __ATOMIC_RELAXED, __HIP_MEMORY_SCOPE_AGENT);
  v.q.b = __hip_atomic_load((const u64*)(p + 4), __ATOMIC_RELAXED, __HIP_MEMORY_SCOPE_AGENT);
  return v.s;
}
__device__ __forceinline__ void wait_slow(const u32* stG, u32 tgt, int lane) {
  const u32* p = stG + (lane & 15) * 16;
  for (;;) {
    u32 s = __hip_atomic_load(p, __ATOMIC_RELAXED, __HIP_MEMORY_SCOPE_AGENT);
    if (__all((int)(s >= tgt))) return;
    __builtin_amdgcn_s_sleep(1);
  }
}

// ---------------- fast (intra-XCD, shared-L2, sc0) exchange ----------------
// Used only after the per-dispatch self-test verified the full producer->L2->
// consumer pipe under the chosen grouping. useinv adds an agent acquire fence
// (cache invalidate) per poll for the stale-L1 hypothesis.
__device__ __forceinline__ u32 poll_ld(const u32* p, int useinv) {
  u32 s;
  if (useinv) __builtin_amdgcn_fence(__ATOMIC_ACQUIRE, "agent");
  asm volatile("global_load_dword %0, %1, off sc0\n\ts_waitcnt vmcnt(0)"
               : "=v"(s) : "v"(p) : "memory");
  return s;
}
__device__ __forceinline__ int wait_fast(const u32* stG, u32 tgt, int lane, int useinv) {
  const u32* p = stG + (lane & 15) * 16;
  int it = 0;
  for (;;) {
    u32 s = poll_ld(p, useinv);
    if (__all((int)(s >= tgt))) return 1;
    if (++it > 16384) return 0;               // ~2 ms: terminate instead of hang
    __builtin_amdgcn_s_sleep(1);
  }
}
// issue-only 16B sc0 load; caller does ONE vmcnt(0) + sched_barrier(0) after batch
__device__ __forceinline__ short8 ldfrag_sc0_issue(const ushort_t* p) {
  short8 v;
  asm volatile("global_load_dwordx4 %0, %1, off sc0" : "=v"(v) : "v"(p));
  return v;
}
// publish: data store -> vmcnt(0) -> stamp store
__device__ __forceinline__ void publish(ushort_t* dp, u64 v, u32* sp, u32 sv,
                                        int leader, int fast) {
  if (fast) {
    asm volatile("global_store_dwordx2 %0, %1, off sc0" :: "v"(dp), "v"(v) : "memory");
    asm volatile("s_waitcnt vmcnt(0)" ::: "memory");
    if (leader)
      asm volatile("global_store_dword %0, %1, off sc0" :: "v"(sp), "v"(sv) : "memory");
  } else {
    __hip_atomic_store((u64*)dp, v, __ATOMIC_RELAXED, __HIP_MEMORY_SCOPE_AGENT);
    asm volatile("s_waitcnt vmcnt(0)" ::: "memory");
    if (leader)
      __hip_atomic_store(sp, sv, __ATOMIC_RELAXED, __HIP_MEMORY_SCOPE_AGENT);
  }
}

// ---- per-group sc0 transport self-test under a given (grp,mem) assignment ----
// Region layout (u32 offsets in tb): td u64[128] @0..255, tstamp lines @256
// (+m*16), tready @512..527. All caps bounded; 2 rounds (repeated-update test).
__device__ int test_sc0(u32* tb, int mem, int lane, int useinv) {
  u64* td = (u64*)tb;
  u32* tstamp = tb + 256;
  u32* tready = tb + 512;
  int ok = 1;
  for (int r = 0; r < 2; ++r) {
    u32 seq = 1u + (u32)r;
    // pollute caches with the current (about-to-be-stale) copies
    { u64 a = td[lane]; u64 b = td[lane + 64]; u32 s = tstamp[(lane & 15) * 16];
      asm volatile("" :: "v"(a), "v"(b), "v"(s)); }
    // round-entry handshake on the proven agent path
    if (lane == 0)
      __hip_atomic_store(tready + mem, seq, __ATOMIC_RELEASE, __HIP_MEMORY_SCOPE_AGENT);
    { int it = 0, hs = 1;
      for (;;) {
        u32 v = __hip_atomic_load(tready + (lane & 15), __ATOMIC_RELAXED,
                                  __HIP_MEMORY_SCOPE_AGENT);
        if (__all((int)(v >= seq))) break;
        if (++it > 16384) { hs = 0; break; }
        __builtin_amdgcn_s_sleep(2);
      }
      if (!hs) return 0; }
    // publish own slots + stamp with the steady-state-exact sc0 sequence
    if (lane < 8) {
      u64 v = 0x9E3779B97F4A7C15ull * (u64)(seq * 131u + (u32)mem * 17u + (u32)lane + 1u);
      asm volatile("global_store_dwordx2 %0, %1, off sc0"
                   :: "v"(td + mem * 8 + lane), "v"(v) : "memory");
    }
    asm volatile("s_waitcnt vmcnt(0)" ::: "memory");
    if (lane == 0)
      asm volatile("global_store_dword %0, %1, off sc0"
                   :: "v"(tstamp + mem * 16), "v"(seq) : "memory");
    // detect via sc0 polls (small cap: a working pipe detects in <16 iters)
    int saw = 0;
    { int it = 0;
      for (;;) {
        u32 s = poll_ld(tstamp + (lane & 15) * 16, useinv);
        if (__all((int)(s >= seq))) { saw = 1; break; }
        if (++it > 128) break;
        __builtin_amdgcn_s_sleep(2);
      } }
    if (!saw) { ok = 0; continue; }   // keep lockstep for round 2 handshake
    // verify all 16 members' slots via sc0 loads
    { u64 a, b;
      if (useinv) __builtin_amdgcn_fence(__ATOMIC_ACQUIRE, "agent");
      asm volatile("global_load_dwordx2 %0, %2, off sc0\n\t"
                   "global_load_dwordx2 %1, %3, off sc0\n\t"
                   "s_waitcnt vmcnt(0)"
                   : "=v"(a), "=v"(b) : "v"(td + lane), "v"(td + lane + 64) : "memory");
      int s0 = lane >> 3, j0 = lane & 7, s1 = (lane + 64) >> 3, j1 = (lane + 64) & 7;
      u64 e0 = 0x9E3779B97F4A7C15ull * (u64)(seq * 131u + (u32)s0 * 17u + (u32)j0 + 1u);
      u64 e1 = 0x9E3779B97F4A7C15ull * (u64)(seq * 131u + (u32)s1 * 17u + (u32)j1 + 1u);
      if (!__all((int)((a == e0) && (b == e1)))) ok = 0;
    }
  }
  return ok;
}

// ---- weight conversion: blob[mem][mat][col][k] bf16, k contiguous ----
__global__ void conv_weights(
    const float* __restrict__ wf, const float* __restrict__ wi,
    const float* __restrict__ wc, const float* __restrict__ wo,
    const float* __restrict__ rf, const float* __restrict__ ri,
    const float* __restrict__ rc, const float* __restrict__ ro,
    const float* __restrict__ pf, const float* __restrict__ pi,
    const float* __restrict__ po, ushort_t* __restrict__ blob)
{
  int id = blockIdx.x * 256 + threadIdx.x;   // 720896 total, exact
  int k   = id & 255;
  int col = (id >> 8) & 15;
  int q   = id >> 12;          // 0..175
  int m   = q % 11;
  int mm  = q / 11;
  const float* srcs[11] = {wf, wi, wc, wo, rf, ri, rc, ro, pf, pi, po};
  float v = srcs[m][k * 256 + mm * 16 + col];
  unsigned u = __float_as_uint(v);
  blob[id] = (ushort_t)((u + 0x7fffu + ((u >> 16) & 1u)) >> 16);
}

// ---- persistent recurrent kernel ----
// Policy (global, decided at runtime by self-test + block-0 consensus):
//  0 = slow (agent/MALL exchange, grouping grp=bid&7)          [baseline]
//  1 = fast sc0, grouping G1 (grp=bid&7   : round-robin XCD dispatch)
//  2 = fast sc0, grouping G2 (grp=bid>>4  : chunked XCD dispatch)
//  3/4 = same as 1/2 but with acquire-fence per poll (stale-L1 hedge)
extern "C" __global__ void __launch_bounds__(128, 1)
lstm_rec(const float* __restrict__ x, const ushort_t* __restrict__ blob,
         ushort_t* __restrict__ h_ex, ushort_t* __restrict__ c_ex,
         u32* __restrict__ stamps, u32* __restrict__ tst, u32* __restrict__ gcon,
         const float* __restrict__ bfv, const float* __restrict__ biv,
         const float* __restrict__ bcv, const float* __restrict__ bov,
         float* __restrict__ out)
{
  __shared__ ushort_t xa[16 * 264];     // x(t) bf16, row stride 264
  __shared__ float pre[4][16][17];      // gate preacts
  __shared__ float pop[16][17];         // po partial (wave1)
  __shared__ float cn_f32[16][16];      // own-col c state, f32
  __shared__ ushort_t cn_bf[16][16];
  __shared__ ushort_t hn_bf[16][16];
  __shared__ float bia[4][16];
  __shared__ int s_mode;

  const int tid = threadIdx.x;
  const int bid = blockIdx.x;
  const int wv = tid >> 6;
  const int lane = tid & 63;
  const int lr = lane & 15;
  const int lk = lane >> 4;

  u32* gok = gcon;          // [128] per-block verdict bitmasks
  u32* gpol = gcon + 256;   // global policy word (own line)

  // ======== transport/placement self-tests (wave 0 only) ========
  if (wv == 0) {
    int ok1 = test_sc0(tst + 0 * 8192 + (bid & 7) * 1024, bid >> 3, lane, 0);   // G1 plain
    int ok2 = test_sc0(tst + 1 * 8192 + (bid >> 4) * 1024, bid & 15, lane, 0);  // G2 plain
    int ok3 = test_sc0(tst + 2 * 8192 + (bid & 7) * 1024, bid >> 3, lane, 1);   // G1 +inv
    int ok4 = test_sc0(tst + 3 * 8192 + (bid >> 4) * 1024, bid & 15, lane, 1);  // G2 +inv
    if (lane == 0) {
      u32 v = 1u | ((u32)ok1 << 1) | ((u32)ok2 << 2) | ((u32)ok3 << 3) | ((u32)ok4 << 4);
      __hip_atomic_store(gok + bid, v, __ATOMIC_RELEASE, __HIP_MEMORY_SCOPE_AGENT);
    }
    if (bid == 0) {           // aggregate all 128 verdicts, publish policy
      u32 pol = 0; int it = 0;
      for (;;) {
        u32 a = __hip_atomic_load(gok + lane, __ATOMIC_RELAXED, __HIP_MEMORY_SCOPE_AGENT);
        u32 b = __hip_atomic_load(gok + 64 + lane, __ATOMIC_RELAXED, __HIP_MEMORY_SCOPE_AGENT);
        if (__all((int)((a & 1u) && (b & 1u)))) {
          if      (__all((int)(((a >> 1) & 1u) && ((b >> 1) & 1u)))) pol = 1;
          else if (__all((int)(((a >> 2) & 1u) && ((b >> 2) & 1u)))) pol = 2;
          else if (__all((int)(((a >> 3) & 1u) && ((b >> 3) & 1u)))) pol = 3;
          else if (__all((int)(((a >> 4) & 1u) && ((b >> 4) & 1u)))) pol = 4;
          break;
        }
        if (++it > 16384) { pol = 0; break; }
        __builtin_amdgcn_s_sleep(4);
      }
      if (lane == 0)
        __hip_atomic_store(gpol, pol + 1u, __ATOMIC_RELEASE, __HIP_MEMORY_SCOPE_AGENT);
    }
    u32 p;
    for (;;) {                // block 0 always publishes (all its waits capped)
      p = __hip_atomic_load(gpol, __ATOMIC_RELAXED, __HIP_MEMORY_SCOPE_AGENT);
      if (p) break;
      __builtin_amdgcn_s_sleep(4);
    }
    if (lane == 0) s_mode = (int)(p - 1u);
  }
  __syncthreads();
  const int policy = s_mode;
  const int fast   = policy != 0;
  const int useinv = policy >= 3;
  const int grpG2  = (policy == 2) || (policy == 4);
  const int grp = grpG2 ? (bid >> 4) : (bid & 7);
  const int mem = grpG2 ? (bid & 15) : (bid >> 3);
  const int gb0 = grp * 16;
  const int gc0 = mem * 16;

  // ---- weight fragments -> registers ----
  const ushort_t* wb = blob + (size_t)mem * CHUNK_ELEMS;
  short8 wXa[8], wXb[8], wRa[8], wRb[8], wPa[8], wPb[8];
  {
    const int m0 = wv ? 2 : 0;
    const int p0 = wv ? 10 : 8;
    const int p1 = wv ? 10 : 9;
#pragma unroll
    for (int s = 0; s < 8; ++s) {
      const int ko = s * 32 + lk * 8;
      wXa[s] = *(const short8*)(wb + ((m0    ) * 16 + lr) * 256 + ko);
      wXb[s] = *(const short8*)(wb + ((m0 + 1) * 16 + lr) * 256 + ko);
      wRa[s] = *(const short8*)(wb + ((m0 + 4) * 16 + lr) * 256 + ko);
      wRb[s] = *(const short8*)(wb + ((m0 + 5) * 16 + lr) * 256 + ko);
      wPa[s] = *(const short8*)(wb + (p0 * 16 + lr) * 256 + ko);
      wPb[s] = *(const short8*)(wb + (p1 * 16 + lr) * 256 + ko);
    }
  }

  if (tid < 64) {
    const float* bs = (tid < 16) ? bfv : (tid < 32) ? biv : (tid < 48) ? bcv : bov;
    bia[tid >> 4][tid & 15] = bs[gc0 + (tid & 15)];
  }
  const int pb = tid >> 3, pc = (tid & 7) * 2;
  cn_f32[pb][pc] = 0.f;
  cn_f32[pb][pc + 1] = 0.f;

  // stage x(0) -> xa (bf16)
  const int xr = tid >> 3, xc = (tid & 7) * 32;
  {
    const float* xp = x + (size_t)(gb0 + xr) * TT * DU + xc;
#pragma unroll
    for (int u = 0; u < 8; ++u) {
      float4 f = *(const float4*)(xp + u * 4);
      u64 pk = (u64)f2bf(f.x) | ((u64)f2bf(f.y) << 16) |
               ((u64)f2bf(f.z) << 32) | ((u64)f2bf(f.w) << 48);
      *(u64*)&xa[xr * 264 + xc + u * 4] = pk;
    }
  }
  __syncthreads();                          // xa ready
  int wedged = 0;

  const floatx4 z4 = {0.f, 0.f, 0.f, 0.f};
  floatx4 accA = z4, accB = z4;
  // prologue: x(0)@W  (c(-1)=0 so no peephole term)
#pragma unroll
  for (int s = 0; s < 8; ++s) {
    short8 a = *(const short8*)&xa[lr * 264 + s * 32 + lk * 8];
    accA = MFMA(a, wXa[s], accA);
    accB = MFMA(a, wXb[s], accB);
  }

  u32* stG = stamps + grp * 256;          // 16 members x 64B line each
  ushort_t* cG = c_ex + grp * 16 * 256;   // 16 slots x 256 ushorts (512 B)
  ushort_t* hG = h_ex + grp * 16 * 256;
  const int sb = lane >> 2, sc = (lane & 3) * 4;

  for (int t = 0; t < TT; ++t) {
    // ---- h-part: wait h(t-1), pre += h(t-1)@R ----
    if (t > 0) {
      if (fast) {
        if (!wedged && !wait_fast(stG, 2u * (u32)t, lane, useinv)) wedged = 1;
        short8 hf[8];
#pragma unroll
        for (int s = 0; s < 8; ++s) {
          int k = s * 32 + lk * 8;
          hf[s] = ldfrag_sc0_issue(hG + (k >> 4) * 256 + lr * 16 + (k & 15));
        }
        asm volatile("s_waitcnt vmcnt(0)" ::: "memory");
        __builtin_amdgcn_sched_barrier(0);
#pragma unroll
        for (int s = 0; s < 8; ++s) {
          accA = MFMA(hf[s], wRa[s], accA);
          accB = MFMA(hf[s], wRb[s], accB);
        }
      } else {
        wait_slow(stG, 2u * (u32)t, lane);
#pragma unroll
        for (int s = 0; s < 8; ++s) {
          int k = s * 32 + lk * 8;
          short8 hf = ldfrag(hG + (k >> 4) * 256 + lr * 16 + (k & 15));
          accA = MFMA(hf, wRa[s], accA);
          accB = MFMA(hf, wRb[s], accB);
        }
      }
    }
#pragma unroll
    for (int r = 0; r < 4; ++r) {
      pre[wv * 2    ][lk * 4 + r][lr] = accA[r];
      pre[wv * 2 + 1][lk * 4 + r][lr] = accB[r];
    }
    __syncthreads();                                  // S1: pre complete

    // ---- pointwise 1: f,i,c~ -> c_new ----
#pragma unroll
    for (int e = 0; e < 2; ++e) {
      int c = pc + e;
      float fg = sigf(pre[0][pb][c] + bia[0][c]);
      float ig = sigf(pre[1][pb][c] + bia[1][c]);
      float ct = tanhf_(pre[2][pb][c] + bia[2][c]);
      float cn = fg * cn_f32[pb][c] + ig * ct;
      cn_f32[pb][c] = cn;
      cn_bf[pb][c] = f2bf(cn);
    }
    __syncthreads();                                  // S2: cn_bf complete

    // ---- publish c ----
    if (wv == 0) {
      u64 v = *(const u64*)&cn_bf[sb][sc];
      publish(cG + mem * 256 + sb * 16 + sc, v, stG + mem * 16,
              2u * (u32)t + 1u, lane == 0, fast);
    }

    // ---- x(t+1) HBM prefetch fills the c-wait window ----
    float4 xf[8];
    if (t < TT - 1) {
      const float* xp = x + ((size_t)(gb0 + xr) * TT + (t + 1)) * DU + xc;
#pragma unroll
      for (int u = 0; u < 8; ++u) xf[u] = *(const float4*)(xp + u * 4);
    }
    if (fast) { if (!wedged && !wait_fast(stG, 2u * (u32)t + 1u, lane, useinv)) wedged = 1; }
    else      wait_slow(stG, 2u * (u32)t + 1u, lane);   // c(t) visible

    // ---- phase B: po matvec (wave1) + next-step peepholes (wave0) ----
    {
      short8 cf[8];
      if (fast) {
#pragma unroll
        for (int s = 0; s < 8; ++s) {
          int k = s * 32 + lk * 8;
          cf[s] = ldfrag_sc0_issue(cG + (k >> 4) * 256 + lr * 16 + (k & 15));
        }
        asm volatile("s_waitcnt vmcnt(0)" ::: "memory");
        __builtin_amdgcn_sched_barrier(0);
      } else {
#pragma unroll
        for (int s = 0; s < 8; ++s) {
          int k = s * 32 + lk * 8;
          cf[s] = ldfrag(cG + (k >> 4) * 256 + lr * 16 + (k & 15));
        }
      }
      if (wv == 0) {
        accA = z4; accB = z4;                          // start step-t+1 accumulators
#pragma unroll
        for (int s = 0; s < 8; ++s) {
          accA = MFMA(cf[s], wPa[s], accA);            // c(t)@pf
          accB = MFMA(cf[s], wPb[s], accB);            // c(t)@pi
        }
      } else {
        floatx4 pacc = z4;
#pragma unroll
        for (int s = 0; s < 8; ++s)
          pacc = MFMA(cf[s], wPa[s], pacc);            // c(t)@po
#pragma unroll
        for (int r = 0; r < 4; ++r) pop[lk * 4 + r][lr] = pacc[r];
      }
    }
    __syncthreads();                                  // S5: pop complete

    // ---- pointwise 2: o gate, h_new ----
#pragma unroll
    for (int e = 0; e < 2; ++e) {
      int c = pc + e;
      float og = sigf(pre[3][pb][c] + pop[pb][c] + bia[3][c]);
      float hv = tanhf_(cn_f32[pb][c]) * og;
      hn_bf[pb][c] = f2bf(hv);
      if (t == TT - 1) out[(gb0 + pb) * 256 + gc0 + c] = hv;
    }
    if (t == TT - 1) break;
    __syncthreads();                                  // S6: hn_bf complete

    // ---- publish h ----
    if (wv == 0) {
      u64 v = *(const u64*)&hn_bf[sb][sc];
      publish(hG + mem * 256 + sb * 16 + sc, v, stG + mem * 16,
              2u * (u32)t + 2u, lane == 0, fast);
    }

    // ---- stage x(t+1) into LDS, then x@W fills the h-wait window ----
#pragma unroll
    for (int u = 0; u < 8; ++u) {
      float4 f = xf[u];
      u64 pk = (u64)f2bf(f.x) | ((u64)f2bf(f.y) << 16) |
               ((u64)f2bf(f.z) << 32) | ((u64)f2bf(f.w) << 48);
      *(u64*)&xa[xr * 264 + xc + u * 4] = pk;
    }
    __syncthreads();                                  // S8: xa ready

    if (wv == 1) { accA = z4; accB = z4; }            // c~,o restart
#pragma unroll
    for (int s = 0; s < 8; ++s) {
      short8 a = *(const short8*)&xa[lr * 264 + s * 32 + lk * 8];
      accA = MFMA(a, wXa[s], accA);
      accB = MFMA(a, wXb[s], accB);
    }
    // loop head waits h-stamps (2t+2) before using h frags
  }
}

extern "C" void kernel_launch(void* const* d_in, const int* in_sizes, int n_in,
                              void* d_out, int out_size, void* d_ws, size_t ws_size,
                              hipStream_t stream) {
  const float* x   = (const float*)d_in[0];
  const float* bfv = (const float*)d_in[12];
  const float* biv = (const float*)d_in[13];
  const float* bcv = (const float*)d_in[14];
  const float* bov = (const float*)d_in[15];
  float* outp = (float*)d_out;

  char* ws = (char*)d_ws;
  ushort_t* c_exp = (ushort_t*)(ws + CEX_OFF);
  ushort_t* h_exp = (ushort_t*)(ws + HEX_OFF);
  u32* stmp = (u32*)(ws + STMP_OFF);
  u32* tstp = (u32*)(ws + TST_OFF);
  u32* gcon = (u32*)(ws + GCON_OFF);
  ushort_t* blob = (ushort_t*)(ws + BLOB_OFF);

  // zero exchange buffers + stamps + test/consensus regions (restart every replay)
  hipMemsetAsync(d_ws, 0, BLOB_OFF, stream);

  hipLaunchKernelGGL(conv_weights, dim3(2816), dim3(256), 0, stream,
                     (const float*)d_in[1], (const float*)d_in[2],
                     (const float*)d_in[3], (const float*)d_in[4],
                     (const float*)d_in[5], (const float*)d_in[6],
                     (const float*)d_in[7], (const float*)d_in[8],
                     (const float*)d_in[9], (const float*)d_in[10],
                     (const float*)d_in[11], blob);

  hipLaunchKernelGGL(lstm_rec, dim3(128), dim3(128), 0, stream,
                     x, (const ushort_t*)blob, h_exp, c_exp, stmp, tstp, gcon,
                     bfv, biv, bcv, bov, outp);
}

// Round 5
// 3981.443 us; speedup vs baseline: 1.8941x; 1.8941x over previous
//
#include <hip/hip_runtime.h>

#define TT 1024
#define DU 256

// workspace layout (bytes)
#define CEX_OFF   0          // bf16 c slots: [8 grp][16 mem][16 b][16 c] (65536 B)
#define HEX_OFF   65536      // bf16 h slots: same layout (65536 B)
#define STMP_OFF  131072     // u32 stamps: [8 grp][16 mem][16 pad] — 64B line per member (8192 B)
#define TST_OFF   139264     // 2 test regions x 8 grp x 4096 B (65536 B)
#define GCON_OFF  204800     // gok[128] u32 @ +0; gpol u32 @ +1024 (2048 B)
#define BLOB_OFF  206848     // 16 member chunks of bf16 weights
#define CHUNK_ELEMS (11*16*256)   // per-member: 11 mats x 16 cols x 256 k

typedef unsigned short ushort_t;
typedef unsigned u32;
typedef unsigned long long u64;
typedef __attribute__((ext_vector_type(8))) short short8;
typedef __attribute__((ext_vector_type(2))) unsigned long long u64x2;
typedef __attribute__((ext_vector_type(4))) float floatx4;

#define MFMA(a, b, c) __builtin_amdgcn_mfma_f32_16x16x32_bf16((a), (b), (c), 0, 0, 0)

__device__ __forceinline__ ushort_t f2bf(float f) {
  unsigned u = __float_as_uint(f);
  return (ushort_t)((u + 0x7fffu + ((u >> 16) & 1u)) >> 16);
}
__device__ __forceinline__ float sigf(float x) { return 1.0f / (1.0f + __expf(-x)); }
__device__ __forceinline__ float tanhf_(float x) {
  float t = 1.0f - 2.0f / (__expf(2.0f * fabsf(x)) + 1.0f);
  return copysignf(t, x);
}

// ---------------- slow (agent/MALL) exchange: proven baseline path ----------------
__device__ __forceinline__ short8 ldfrag(const ushort_t* p) {
  union { struct { u64 a, b; } q; short8 s; } v;
  v.q.a = __hip_atomic_load((const u64*)p,       __ATOMIC_RELAXED, __HIP_MEMORY_SCOPE_AGENT);
  v.q.b = __hip_atomic_load((const u64*)(p + 4), __ATOMIC_RELAXED, __HIP_MEMORY_SCOPE_AGENT);
  return v.s;
}
__device__ __forceinline__ void wait_slow(const u32* stG, u32 tgt, int lane) {
  const u32* p = stG + (lane & 15) * 16;
  for (;;) {
    u32 s = __hip_atomic_load(p, __ATOMIC_RELAXED, __HIP_MEMORY_SCOPE_AGENT);
    if (__all((int)(s >= tgt))) return;
    __builtin_amdgcn_s_sleep(1);
  }
}

// ---------------- fast (intra-XCD shared-L2, nt-discipline) exchange ----------------
// Producer: PLAIN stores (write-through, no L1 allocate -> dirty line in the
// shared XCD L2) -> vmcnt(0) -> plain stamp store.
// Consumer: nt loads (no L1 allocate) -> always served by the shared L2.
// Discipline: exchange lines are NEVER plain-loaded, so no stale L1 copy can
// exist (one acquire fence at init clears any pre-history). The self-test
// below verifies this exact pipe end-to-end at runtime; otherwise slow mode.
__device__ __forceinline__ u32 poll_nt(const u32* p) {
  u32 s;
  asm volatile("global_load_dword %0, %1, off nt\n\ts_waitcnt vmcnt(0)"
               : "=v"(s) : "v"(p) : "memory");
  return s;
}
__device__ __forceinline__ int wait_fast(const u32* stG, u32 tgt, int lane) {
  const u32* p = stG + (lane & 15) * 16;
  int it = 0;
  for (;;) {
    u32 s = poll_nt(p);
    if (__all((int)(s >= tgt))) return 1;
    if (++it > 16384) return 0;               // bounded: never hang
    __builtin_amdgcn_s_sleep(1);
  }
}
// nt 16B fragment load — builtin (NOT asm) so the compiler tracks the dep and
// pipelines these with the consuming MFMAs via staged vmcnt (no serialization).
__device__ __forceinline__ short8 ldfrag_nt(const ushort_t* p) {
  union { u64x2 q; short8 s; } v;
  v.q = __builtin_nontemporal_load((const u64x2*)p);
  return v.s;
}
// publish: data store -> vmcnt(0) -> stamp store
__device__ __forceinline__ void publish(ushort_t* dp, u64 v, u32* sp, u32 sv,
                                        int leader, int fast) {
  if (fast) {
    asm volatile("global_store_dwordx2 %0, %1, off" :: "v"(dp), "v"(v) : "memory");
    asm volatile("s_waitcnt vmcnt(0)" ::: "memory");
    if (leader)
      asm volatile("global_store_dword %0, %1, off" :: "v"(sp), "v"(sv) : "memory");
  } else {
    __hip_atomic_store((u64*)dp, v, __ATOMIC_RELAXED, __HIP_MEMORY_SCOPE_AGENT);
    asm volatile("s_waitcnt vmcnt(0)" ::: "memory");
    if (leader)
      __hip_atomic_store(sp, sv, __ATOMIC_RELAXED, __HIP_MEMORY_SCOPE_AGENT);
  }
}

// ---- per-group nt-pipe self-test (representative: NO artificial pollution;
// 3 rounds with round-dependent data catches any L1-allocation staleness).
// Region layout (u32 offs): td u64[128] @0..255, tstamp lines @256 (+m*16),
// tready @512..527. All waits capped.
__device__ int test_nt(u32* tb, int mem, int lane) {
  u64* td = (u64*)tb;
  u32* tstamp = tb + 256;
  u32* tready = tb + 512;
  int ok = 1;
  for (int r = 0; r < 3; ++r) {
    u32 seq = 1u + (u32)r;
    // round-entry handshake on the proven agent path
    if (lane == 0)
      __hip_atomic_store(tready + mem, seq, __ATOMIC_RELEASE, __HIP_MEMORY_SCOPE_AGENT);
    { int it = 0;
      for (;;) {
        u32 v = __hip_atomic_load(tready + (lane & 15), __ATOMIC_RELAXED,
                                  __HIP_MEMORY_SCOPE_AGENT);
        if (__all((int)(v >= seq))) break;
        if (++it > 16384) return 0;
        __builtin_amdgcn_s_sleep(2);
      } }
    // publish own slot + stamp with the steady-state-exact sequence
    if (lane < 8) {
      u64 v = 0x9E3779B97F4A7C15ull * (u64)(seq * 131u + (u32)mem * 17u + (u32)lane + 1u);
      asm volatile("global_store_dwordx2 %0, %1, off"
                   :: "v"(td + mem * 8 + lane), "v"(v) : "memory");
    }
    asm volatile("s_waitcnt vmcnt(0)" ::: "memory");
    if (lane == 0)
      asm volatile("global_store_dword %0, %1, off"
                   :: "v"(tstamp + mem * 16), "v"(seq) : "memory");
    // detect via nt polls (working pipe detects in <16 iters)
    int saw = 0;
    { int it = 0;
      for (;;) {
        u32 s = poll_nt(tstamp + (lane & 15) * 16);
        if (__all((int)(s >= seq))) { saw = 1; break; }
        if (++it > 192) break;
        __builtin_amdgcn_s_sleep(2);
      } }
    if (!saw) { ok = 0; continue; }   // keep lockstep for later rounds
    // verify all 16 slots via nt loads
    u64 a = __builtin_nontemporal_load(td + lane);
    u64 b = __builtin_nontemporal_load(td + lane + 64);
    int s0 = lane >> 3, j0 = lane & 7, s1 = (lane + 64) >> 3, j1 = (lane + 64) & 7;
    u64 e0 = 0x9E3779B97F4A7C15ull * (u64)(seq * 131u + (u32)s0 * 17u + (u32)j0 + 1u);
    u64 e1 = 0x9E3779B97F4A7C15ull * (u64)(seq * 131u + (u32)s1 * 17u + (u32)j1 + 1u);
    if (!__all((int)((a == e0) && (b == e1)))) ok = 0;
  }
  return ok;
}

// ---- weight conversion: blob[mem][mat][col][k] bf16, k contiguous ----
__global__ void conv_weights(
    const float* __restrict__ wf, const float* __restrict__ wi,
    const float* __restrict__ wc, const float* __restrict__ wo,
    const float* __restrict__ rf, const float* __restrict__ ri,
    const float* __restrict__ rc, const float* __restrict__ ro,
    const float* __restrict__ pf, const float* __restrict__ pi,
    const float* __restrict__ po, ushort_t* __restrict__ blob)
{
  int id = blockIdx.x * 256 + threadIdx.x;   // 720896 total, exact
  int k   = id & 255;
  int col = (id >> 8) & 15;
  int q   = id >> 12;          // 0..175
  int m   = q % 11;
  int mm  = q / 11;
  const float* srcs[11] = {wf, wi, wc, wo, rf, ri, rc, ro, pf, pi, po};
  float v = srcs[m][k * 256 + mm * 16 + col];
  unsigned u = __float_as_uint(v);
  blob[id] = (ushort_t)((u + 0x7fffu + ((u >> 16) & 1u)) >> 16);
}

// ---- persistent recurrent kernel ----
// Policy (runtime self-test + block-0 consensus):
//  0 = slow (agent/MALL exchange, grouping grp=bid&7)        [baseline]
//  1 = fast nt, grouping G2 (grp=bid>>4 : chunked dispatch — R4 evidence)
//  2 = fast nt, grouping G1 (grp=bid&7  : round-robin dispatch fallback)
extern "C" __global__ void __launch_bounds__(128, 1)
lstm_rec(const float* __restrict__ x, const ushort_t* __restrict__ blob,
         ushort_t* __restrict__ h_ex, ushort_t* __restrict__ c_ex,
         u32* __restrict__ stamps, u32* __restrict__ tst, u32* __restrict__ gcon,
         const float* __restrict__ bfv, const float* __restrict__ biv,
         const float* __restrict__ bcv, const float* __restrict__ bov,
         float* __restrict__ out)
{
  __shared__ ushort_t xa[16 * 264];     // x(t) bf16, row stride 264
  __shared__ float pre[4][16][17];      // gate preacts
  __shared__ float pop[16][17];         // po partial (wave1)
  __shared__ float cn_f32[16][16];      // own-col c state, f32
  __shared__ ushort_t cn_bf[16][16];
  __shared__ ushort_t hn_bf[16][16];
  __shared__ float bia[4][16];
  __shared__ int s_mode;

  const int tid = threadIdx.x;
  const int bid = blockIdx.x;
  const int wv = tid >> 6;
  const int lane = tid & 63;
  const int lr = lane & 15;
  const int lk = lane >> 4;

  u32* gok = gcon;          // [128] per-block verdict bitmasks
  u32* gpol = gcon + 256;   // global policy word (own line)

  // ======== transport/placement self-tests (wave 0 only) ========
  if (wv == 0) {
    __builtin_amdgcn_fence(__ATOMIC_ACQUIRE, "agent");   // clear L1 pre-history
    int okG2 = test_nt(tst + 0 * 8192 + (bid >> 4) * 1024, bid & 15, lane);
    int okG1 = test_nt(tst + 1 * 8192 + (bid & 7) * 1024, bid >> 3, lane);
    if (lane == 0) {
      u32 v = 1u | ((u32)okG2 << 1) | ((u32)okG1 << 2);
      __hip_atomic_store(gok + bid, v, __ATOMIC_RELEASE, __HIP_MEMORY_SCOPE_AGENT);
    }
    if (bid == 0) {           // aggregate all 128 verdicts, publish policy
      u32 pol = 0; int it = 0;
      for (;;) {
        u32 a = __hip_atomic_load(gok + lane, __ATOMIC_RELAXED, __HIP_MEMORY_SCOPE_AGENT);
        u32 b = __hip_atomic_load(gok + 64 + lane, __ATOMIC_RELAXED, __HIP_MEMORY_SCOPE_AGENT);
        if (__all((int)((a & 1u) && (b & 1u)))) {
          if      (__all((int)(((a >> 1) & 1u) && ((b >> 1) & 1u)))) pol = 1;
          else if (__all((int)(((a >> 2) & 1u) && ((b >> 2) & 1u)))) pol = 2;
          break;
        }
        if (++it > 32768) { pol = 0; break; }
        __builtin_amdgcn_s_sleep(4);
      }
      if (lane == 0)
        __hip_atomic_store(gpol, pol + 1u, __ATOMIC_RELEASE, __HIP_MEMORY_SCOPE_AGENT);
    }
    u32 p;
    for (;;) {                // block 0 always publishes (all its waits capped)
      p = __hip_atomic_load(gpol, __ATOMIC_RELAXED, __HIP_MEMORY_SCOPE_AGENT);
      if (p) break;
      __builtin_amdgcn_s_sleep(4);
    }
    if (lane == 0) s_mode = (int)(p - 1u);
  }
  __syncthreads();
  const int policy = s_mode;
  const int fast   = policy != 0;
  const int grpG2  = (policy == 1);
  const int grp = grpG2 ? (bid >> 4) : (bid & 7);
  const int mem = grpG2 ? (bid & 15) : (bid >> 3);
  const int gb0 = grp * 16;
  const int gc0 = mem * 16;
  if (fast) __builtin_amdgcn_fence(__ATOMIC_ACQUIRE, "agent");  // once, pre-loop

  // ---- weight fragments -> registers ----
  const ushort_t* wb = blob + (size_t)mem * CHUNK_ELEMS;
  short8 wXa[8], wXb[8], wRa[8], wRb[8], wPa[8], wPb[8];
  {
    const int m0 = wv ? 2 : 0;
    const int p0 = wv ? 10 : 8;
    const int p1 = wv ? 10 : 9;
#pragma unroll
    for (int s = 0; s < 8; ++s) {
      const int ko = s * 32 + lk * 8;
      wXa[s] = *(const short8*)(wb + ((m0    ) * 16 + lr) * 256 + ko);
      wXb[s] = *(const short8*)(wb + ((m0 + 1) * 16 + lr) * 256 + ko);
      wRa[s] = *(const short8*)(wb + ((m0 + 4) * 16 + lr) * 256 + ko);
      wRb[s] = *(const short8*)(wb + ((m0 + 5) * 16 + lr) * 256 + ko);
      wPa[s] = *(const short8*)(wb + (p0 * 16 + lr) * 256 + ko);
      wPb[s] = *(const short8*)(wb + (p1 * 16 + lr) * 256 + ko);
    }
  }

  if (tid < 64) {
    const float* bs = (tid < 16) ? bfv : (tid < 32) ? biv : (tid < 48) ? bcv : bov;
    bia[tid >> 4][tid & 15] = bs[gc0 + (tid & 15)];
  }
  const int pb = tid >> 3, pc = (tid & 7) * 2;
  cn_f32[pb][pc] = 0.f;
  cn_f32[pb][pc + 1] = 0.f;

  // stage x(0) -> xa (bf16)
  const int xr = tid >> 3, xc = (tid & 7) * 32;
  {
    const float* xp = x + (size_t)(gb0 + xr) * TT * DU + xc;
#pragma unroll
    for (int u = 0; u < 8; ++u) {
      float4 f = *(const float4*)(xp + u * 4);
      u64 pk = (u64)f2bf(f.x) | ((u64)f2bf(f.y) << 16) |
               ((u64)f2bf(f.z) << 32) | ((u64)f2bf(f.w) << 48);
      *(u64*)&xa[xr * 264 + xc + u * 4] = pk;
    }
  }
  __syncthreads();                          // xa ready
  int wedged = 0;

  const floatx4 z4 = {0.f, 0.f, 0.f, 0.f};
  floatx4 accA = z4, accB = z4;
  // prologue: x(0)@W  (c(-1)=0 so no peephole term)
#pragma unroll
  for (int s = 0; s < 8; ++s) {
    short8 a = *(const short8*)&xa[lr * 264 + s * 32 + lk * 8];
    accA = MFMA(a, wXa[s], accA);
    accB = MFMA(a, wXb[s], accB);
  }

  u32* stG = stamps + grp * 256;          // 16 members x 64B line each
  ushort_t* cG = c_ex + grp * 16 * 256;   // 16 slots x 256 ushorts (512 B)
  ushort_t* hG = h_ex + grp * 16 * 256;
  const int sb = lane >> 2, sc = (lane & 3) * 4;

  for (int t = 0; t < TT; ++t) {
    // ---- h-part: wait h(t-1), pre += h(t-1)@R ----
    if (t > 0) {
      if (fast) {
        if (!wedged && !wait_fast(stG, 2u * (u32)t, lane)) wedged = 1;
#pragma unroll
        for (int s = 0; s < 8; ++s) {
          int k = s * 32 + lk * 8;
          short8 hf = ldfrag_nt(hG + (k >> 4) * 256 + lr * 16 + (k & 15));
          accA = MFMA(hf, wRa[s], accA);
          accB = MFMA(hf, wRb[s], accB);
        }
      } else {
        wait_slow(stG, 2u * (u32)t, lane);
#pragma unroll
        for (int s = 0; s < 8; ++s) {
          int k = s * 32 + lk * 8;
          short8 hf = ldfrag(hG + (k >> 4) * 256 + lr * 16 + (k & 15));
          accA = MFMA(hf, wRa[s], accA);
          accB = MFMA(hf, wRb[s], accB);
        }
      }
    }
#pragma unroll
    for (int r = 0; r < 4; ++r) {
      pre[wv * 2    ][lk * 4 + r][lr] = accA[r];
      pre[wv * 2 + 1][lk * 4 + r][lr] = accB[r];
    }
    __syncthreads();                                  // S1: pre complete

    // ---- pointwise 1: f,i,c~ -> c_new ----
#pragma unroll
    for (int e = 0; e < 2; ++e) {
      int c = pc + e;
      float fg = sigf(pre[0][pb][c] + bia[0][c]);
      float ig = sigf(pre[1][pb][c] + bia[1][c]);
      float ct = tanhf_(pre[2][pb][c] + bia[2][c]);
      float cn = fg * cn_f32[pb][c] + ig * ct;
      cn_f32[pb][c] = cn;
      cn_bf[pb][c] = f2bf(cn);
    }
    __syncthreads();                                  // S2: cn_bf complete

    // ---- publish c ----
    if (wv == 0) {
      u64 v = *(const u64*)&cn_bf[sb][sc];
      publish(cG + mem * 256 + sb * 16 + sc, v, stG + mem * 16,
              2u * (u32)t + 1u, lane == 0, fast);
    }

    // ---- x(t+1) HBM prefetch fills the c-wait window ----
    float4 xf[8];
    if (t < TT - 1) {
      const float* xp = x + ((size_t)(gb0 + xr) * TT + (t + 1)) * DU + xc;
#pragma unroll
      for (int u = 0; u < 8; ++u) xf[u] = *(const float4*)(xp + u * 4);
    }
    if (fast) { if (!wedged && !wait_fast(stG, 2u * (u32)t + 1u, lane)) wedged = 1; }
    else      wait_slow(stG, 2u * (u32)t + 1u, lane);   // c(t) visible

    // ---- phase B: po matvec (wave1) + next-step peepholes (wave0) ----
    {
      short8 cf[8];
      if (fast) {
#pragma unroll
        for (int s = 0; s < 8; ++s) {
          int k = s * 32 + lk * 8;
          cf[s] = ldfrag_nt(cG + (k >> 4) * 256 + lr * 16 + (k & 15));
        }
      } else {
#pragma unroll
        for (int s = 0; s < 8; ++s) {
          int k = s * 32 + lk * 8;
          cf[s] = ldfrag(cG + (k >> 4) * 256 + lr * 16 + (k & 15));
        }
      }
      if (wv == 0) {
        accA = z4; accB = z4;                          // start step-t+1 accumulators
#pragma unroll
        for (int s = 0; s < 8; ++s) {
          accA = MFMA(cf[s], wPa[s], accA);            // c(t)@pf
          accB = MFMA(cf[s], wPb[s], accB);            // c(t)@pi
        }
      } else {
        floatx4 pacc = z4;
#pragma unroll
        for (int s = 0; s < 8; ++s)
          pacc = MFMA(cf[s], wPa[s], pacc);            // c(t)@po
#pragma unroll
        for (int r = 0; r < 4; ++r) pop[lk * 4 + r][lr] = pacc[r];
      }
    }
    __syncthreads();                                  // S5: pop complete

    // ---- pointwise 2: o gate, h_new ----
#pragma unroll
    for (int e = 0; e < 2; ++e) {
      int c = pc + e;
      float og = sigf(pre[3][pb][c] + pop[pb][c] + bia[3][c]);
      float hv = tanhf_(cn_f32[pb][c]) * og;
      hn_bf[pb][c] = f2bf(hv);
      if (t == TT - 1) out[(gb0 + pb) * 256 + gc0 + c] = hv;
    }
    if (t == TT - 1) break;
    __syncthreads();                                  // S6: hn_bf complete

    // ---- publish h ----
    if (wv == 0) {
      u64 v = *(const u64*)&hn_bf[sb][sc];
      publish(hG + mem * 256 + sb * 16 + sc, v, stG + mem * 16,
              2u * (u32)t + 2u, lane == 0, fast);
    }

    // ---- stage x(t+1) into LDS, then x@W fills the h-wait window ----
#pragma unroll
    for (int u = 0; u < 8; ++u) {
      float4 f = xf[u];
      u64 pk = (u64)f2bf(f.x) | ((u64)f2bf(f.y) << 16) |
               ((u64)f2bf(f.z) << 32) | ((u64)f2bf(f.w) << 48);
      *(u64*)&xa[xr * 264 + xc + u * 4] = pk;
    }
    __syncthreads();                                  // S8: xa ready

    if (wv == 1) { accA = z4; accB = z4; }            // c~,o restart
#pragma unroll
    for (int s = 0; s < 8; ++s) {
      short8 a = *(const short8*)&xa[lr * 264 + s * 32 + lk * 8];
      accA = MFMA(a, wXa[s], accA);
      accB = MFMA(a, wXb[s], accB);
    }
    // loop head waits h-stamps (2t+2) before using h frags
  }
}

extern "C" void kernel_launch(void* const* d_in, const int* in_sizes, int n_in,
                              void* d_out, int out_size, void* d_ws, size_t ws_size,
                              hipStream_t stream) {
  const float* x   = (const float*)d_in[0];
  const float* bfv = (const float*)d_in[12];
  const float* biv = (const float*)d_in[13];
  const float* bcv = (const float*)d_in[14];
  const float* bov = (const float*)d_in[15];
  float* outp = (float*)d_out;

  char* ws = (char*)d_ws;
  ushort_t* c_exp = (ushort_t*)(ws + CEX_OFF);
  ushort_t* h_exp = (ushort_t*)(ws + HEX_OFF);
  u32* stmp = (u32*)(ws + STMP_OFF);
  u32* tstp = (u32*)(ws + TST_OFF);
  u32* gcon = (u32*)(ws + GCON_OFF);
  ushort_t* blob = (ushort_t*)(ws + BLOB_OFF);

  // zero exchange buffers + stamps + test/consensus regions (restart every replay)
  hipMemsetAsync(d_ws, 0, BLOB_OFF, stream);

  hipLaunchKernelGGL(conv_weights, dim3(2816), dim3(256), 0, stream,
                     (const float*)d_in[1], (const float*)d_in[2],
                     (const float*)d_in[3], (const float*)d_in[4],
                     (const float*)d_in[5], (const float*)d_in[6],
                     (const float*)d_in[7], (const float*)d_in[8],
                     (const float*)d_in[9], (const float*)d_in[10],
                     (const float*)d_in[11], blob);

  hipLaunchKernelGGL(lstm_rec, dim3(128), dim3(128), 0, stream,
                     x, (const ushort_t*)blob, h_exp, c_exp, stmp, tstp, gcon,
                     bfv, biv, bcv, bov, outp);
}